// Round 2
// baseline (131.167 us; speedup 1.0000x reference)
//
#include <hip/hip_runtime.h>
#include <hip/hip_cooperative_groups.h>

namespace cg = cooperative_groups;

// CRPS ensemble loss, single cooperative kernel (one graph node, no memset,
// no atomics).
//   term1 = mean_i |s_i - y|                  (per pixel)
//   term2 = 0.5 * mean_{i,j} |s_i - s_j| = (1/N^2) * sum_{i<j} |s_i - s_j|
//   out   = mean_p (term1 - term2)
// N = 16 samples, P = B*C*H*W = 262144 pixels, fp32.
//
// Structure: one thread per float2; all 16 samples cached in registers;
// O(N^2) pair sum in-register. Per-block partial -> d_ws[blockIdx]
// (fully overwritten every run, so workspace poison is harmless),
// grid-wide sync, block 0 reduces the 512 partials and writes out[0].
// Rationale (round-1 counters): kernel math is ~3 us; the measured 71 us
// was dominated by the harness's 256 MiB poison fill (~43 us, not ours to
// fix) plus ~25 us of graph-node overhead (memset node + atomic tail).
// This version has exactly ONE node and no inter-node dependency.

#define NS 16

__global__ __launch_bounds__(256) void crps_coop(
    const float* __restrict__ samples,
    const float* __restrict__ target,
    float* __restrict__ partials,
    float* __restrict__ out,
    int P /* pixels, even */, float scale /* 1/P */) {

    const int tid = blockIdx.x * blockDim.x + threadIdx.x;  // float2-group idx
    const int P2 = P >> 1;

    float local = 0.0f;
    if (tid < P2) {
        const float2 y2 = reinterpret_cast<const float2*>(target)[tid];
        const float yv[2] = {y2.x, y2.y};

        // Cache all 16 samples for this float2 group in registers.
        // 17 independent 8B loads issued back-to-back -> full MLP.
        float s[NS][2];
#pragma unroll
        for (int i = 0; i < NS; ++i) {
            const float2 v =
                reinterpret_cast<const float2*>(samples)[(size_t)i * P2 + tid];
            s[i][0] = v.x; s[i][1] = v.y;
        }

#pragma unroll
        for (int c = 0; c < 2; ++c) {
            float sum1 = 0.0f;  // sum_i |s_i - y|
            float sum2 = 0.0f;  // sum_{i<j} |s_i - s_j|
#pragma unroll
            for (int i = 0; i < NS; ++i) {
                sum1 += fabsf(s[i][c] - yv[c]);
#pragma unroll
                for (int j = i + 1; j < NS; ++j) {
                    sum2 += fabsf(s[i][c] - s[j][c]);
                }
            }
            // term1 - term2 = sum1/N - sum2/N^2
            local += sum1 * (1.0f / (float)NS)
                   - sum2 * (1.0f / (float)(NS * NS));
        }
    }

    // wave(64) shuffle reduction, then LDS combine of the 4 waves.
    #pragma unroll
    for (int off = 32; off > 0; off >>= 1)
        local += __shfl_down(local, off, 64);

    __shared__ float wsum[4];  // 256 threads = 4 waves
    const int lane = threadIdx.x & 63;
    const int wid  = threadIdx.x >> 6;
    if (lane == 0) wsum[wid] = local;
    __syncthreads();
    if (threadIdx.x == 0)
        partials[blockIdx.x] = wsum[0] + wsum[1] + wsum[2] + wsum[3];

    // Make partials visible device-wide, then grid-wide barrier.
    __threadfence();
    cg::this_grid().sync();

    // Block 0 finishes: 512 partials -> scalar.
    if (blockIdx.x == 0) {
        float l2 = 0.0f;
        for (int i = threadIdx.x; i < (int)gridDim.x; i += blockDim.x)
            l2 += partials[i];

        #pragma unroll
        for (int off = 32; off > 0; off >>= 1)
            l2 += __shfl_down(l2, off, 64);

        if (lane == 0) wsum[wid] = l2;  // safe: grid sync ordered prior use
        __syncthreads();
        if (threadIdx.x == 0)
            out[0] = (wsum[0] + wsum[1] + wsum[2] + wsum[3]) * scale;
    }
}

extern "C" void kernel_launch(void* const* d_in, const int* in_sizes, int n_in,
                              void* d_out, int out_size, void* d_ws, size_t ws_size,
                              hipStream_t stream) {
    const float* samples = (const float*)d_in[0];  // [N, P]
    const float* target  = (const float*)d_in[1];  // [P]
    float* out = (float*)d_out;
    float* partials = (float*)d_ws;

    const int P  = in_sizes[1];          // 262144
    const int P2 = P >> 1;               // 131072
    const int threads = 256;
    const int blocks  = (P2 + threads - 1) / threads;  // 512 (2 blocks/CU,
                                                       // co-resident: OK for
                                                       // cooperative launch)
    float scale = 1.0f / (float)P;

    void* args[] = {(void*)&samples, (void*)&target, (void*)&partials,
                    (void*)&out, (void*)&P, (void*)&scale};
    hipLaunchCooperativeKernel((void*)crps_coop, dim3(blocks), dim3(threads),
                               args, 0, stream);
}

// Round 3
// 68.029 us; speedup vs baseline: 1.9281x; 1.9281x over previous
//
#include <hip/hip_runtime.h>

// CRPS ensemble loss, single kernel, single graph node.
//   term1 = mean_i |s_i - y|                  (per pixel)
//   term2 = 0.5 * mean_{i,j} |s_i - s_j| = (1/N^2) * sum_{i<j} |s_i - s_j|
//   out   = mean_p (term1 - term2)
// N = 16 samples, P = B*C*H*W = 262144 pixels, fp32.
//
// Round-2 lesson: cg::this_grid().sync() cost ~50 us (512 blocks x
// contended device-scope atomics across 8 non-coherent XCD L2s), and
// round-1's 512 same-address atomicAdds had the same disease. This
// version has NO contended operation:
//   - each block release-stores its partial into its OWN d_ws slot as a
//     self-validating 8B pair (bits, bits^MASK). Poison (any constant
//     fill) can never satisfy hi == lo^MASK, so no zero-init needed and
//     stale workspace cannot be consumed.
//   - block 0 acquire-loads the slots (one slot per lane -> no
//     contention), spins until each validates, then reduces and writes
//     out[0]. Blocks progress independently -> no residency requirement,
//     no deadlock.
// Compute structure + fp accumulation order identical to the round-0
// kernel pair (absmax 0.0).

#define NS 16
#define VMASK 0xA5A5A5A5u

__global__ __launch_bounds__(256) void crps_one(
    const float* __restrict__ samples,
    const float* __restrict__ target,
    unsigned long long* __restrict__ slots,  // d_ws, one u64 per block
    float* __restrict__ out,
    int P /* pixels, divisible by 4 */, float scale /* 1/P */) {

    const int tid = blockIdx.x * blockDim.x + threadIdx.x;  // float4-group idx
    const int P4 = P >> 2;

    float local = 0.0f;
    if (tid < P4) {
        const float4 y4 = reinterpret_cast<const float4*>(target)[tid];
        const float yv[4] = {y4.x, y4.y, y4.z, y4.w};

        // Cache all 16 samples for this float4 group in registers.
        float s[NS][4];
#pragma unroll
        for (int i = 0; i < NS; ++i) {
            const float4 v =
                reinterpret_cast<const float4*>(samples + (size_t)i * P)[tid];
            s[i][0] = v.x; s[i][1] = v.y; s[i][2] = v.z; s[i][3] = v.w;
        }

#pragma unroll
        for (int c = 0; c < 4; ++c) {
            float sum1 = 0.0f;  // sum_i |s_i - y|
            float sum2 = 0.0f;  // sum_{i<j} |s_i - s_j|
#pragma unroll
            for (int i = 0; i < NS; ++i) {
                sum1 += fabsf(s[i][c] - yv[c]);
#pragma unroll
                for (int j = i + 1; j < NS; ++j) {
                    sum2 += fabsf(s[i][c] - s[j][c]);
                }
            }
            // term1 - term2 = sum1/N - sum2/N^2
            local += sum1 * (1.0f / (float)NS)
                   - sum2 * (1.0f / (float)(NS * NS));
        }
    }

    // wave(64) shuffle reduction, then LDS combine of the 4 waves.
#pragma unroll
    for (int off = 32; off > 0; off >>= 1)
        local += __shfl_down(local, off, 64);

    __shared__ float wsum[4];  // 256 threads = 4 waves
    const int lane = threadIdx.x & 63;
    const int wid  = threadIdx.x >> 6;
    if (lane == 0) wsum[wid] = local;
    __syncthreads();

    if (threadIdx.x == 0) {
        const float bsum = wsum[0] + wsum[1] + wsum[2] + wsum[3];
        const unsigned int b = __float_as_uint(bsum);
        const unsigned long long pack =
            (unsigned long long)b |
            ((unsigned long long)(b ^ VMASK) << 32);
        // Device-scope release store: visible across XCDs.
        __hip_atomic_store(&slots[blockIdx.x], pack, __ATOMIC_RELEASE,
                           __HIP_MEMORY_SCOPE_AGENT);
    }

    // Block 0 finishes: poll all slots (1 per lane, non-contended reads),
    // then reduce exactly like the old finish kernel.
    if (blockIdx.x == 0) {
        float l2 = 0.0f;
        for (int i = threadIdx.x; i < (int)gridDim.x; i += blockDim.x) {
            unsigned long long v;
            for (;;) {
                v = __hip_atomic_load(&slots[i], __ATOMIC_ACQUIRE,
                                      __HIP_MEMORY_SCOPE_AGENT);
                const unsigned int lo = (unsigned int)v;
                const unsigned int hi = (unsigned int)(v >> 32);
                if (hi == (lo ^ VMASK)) break;
                __builtin_amdgcn_s_sleep(1);
            }
            l2 += __uint_as_float((unsigned int)v);
        }

#pragma unroll
        for (int off = 32; off > 0; off >>= 1)
            l2 += __shfl_down(l2, off, 64);

        if (lane == 0) wsum[wid] = l2;  // safe: only thread 0 read wsum above
        __syncthreads();
        if (threadIdx.x == 0)
            out[0] = (wsum[0] + wsum[1] + wsum[2] + wsum[3]) * scale;
    }
}

extern "C" void kernel_launch(void* const* d_in, const int* in_sizes, int n_in,
                              void* d_out, int out_size, void* d_ws, size_t ws_size,
                              hipStream_t stream) {
    const float* samples = (const float*)d_in[0];  // [N, P]
    const float* target  = (const float*)d_in[1];  // [P]
    float* out = (float*)d_out;
    unsigned long long* slots = (unsigned long long*)d_ws;

    const int P  = in_sizes[1];          // 262144
    const int P4 = P >> 2;               // 65536
    const int threads = 256;
    const int blocks  = (P4 + threads - 1) / threads;  // 256

    float scale = 1.0f / (float)P;
    crps_one<<<blocks, threads, 0, stream>>>(samples, target, slots, out, P,
                                             scale);
}